// Round 13
// baseline (154.638 us; speedup 1.0000x reference)
//
#include <hip/hip_runtime.h>

#define HH 128
#define WW 128
#define NPIX 16384
#define NC 32
#define NO 32
#define KS 9
#define TAPS 81
#define DIL 2
#define PAD 8
#define SMAX 27.6310211159f   // s <= SMAX <=> exp(-0.5 s) >= 1e-6; dropped-tap bound ~1.4e-5 << tol
#define NW (NO * NC * TAPS)   // 82944
#define CAP 262144            // fallback-A list capacity

// ---------------------------------------------------------------------------
// Per-pixel mask record: 32 bytes, byte iz = i*3+z holds the 3-bit live mask
// for taps j in {3z,3z+1,3z+2} of row i (bytes 27..31 never read).
// Written byte-owned by prep threads (no atomics), read as 2x uint4.
// ---------------------------------------------------------------------------
#define BUILD_MASK32(P, M0, M1) do {                                        \
        const uint4* mp_ = (const uint4*)(mask32 + (size_t)(P) * 32);       \
        uint4 ma_ = mp_[0], mb_ = mp_[1];                                   \
        unsigned w_[8] = { ma_.x, ma_.y, ma_.z, ma_.w,                      \
                           mb_.x, mb_.y, mb_.z, mb_.w };                    \
        M0 = 0ull; M1 = 0u;                                                 \
        unsigned m9_[9];                                                    \
        _Pragma("unroll")                                                   \
        for (int i_ = 0; i_ < 9; ++i_) {                                    \
            int k0_ = 3 * i_, k1_ = 3 * i_ + 1, k2_ = 3 * i_ + 2;           \
            unsigned b0_ = (w_[k0_ >> 2] >> ((k0_ & 3) * 8)) & 7u;          \
            unsigned b1_ = (w_[k1_ >> 2] >> ((k1_ & 3) * 8)) & 7u;          \
            unsigned b2_ = (w_[k2_ >> 2] >> ((k2_ & 3) * 8)) & 7u;          \
            m9_[i_] = b0_ | (b1_ << 3) | (b2_ << 6);                        \
        }                                                                   \
        _Pragma("unroll")                                                   \
        for (int i_ = 0; i_ < 7; ++i_)                                      \
            M0 |= (unsigned long long)m9_[i_] << (9 * i_);                  \
        M0 |= (unsigned long long)(m9_[7] & 1u) << 63;                      \
        M1 = (m9_[7] >> 1) | (m9_[8] << 8);                                 \
    } while (0)

// ---------------------------------------------------------------------------
// D1 (prep4): roles by blockIdx.x:
//   [0,432)   prep as SHIFT-CORRELATION: thread owns (iz, 4 consecutive
//             pixels). FAST path (~99.9% of threads): two aligned float2
//             loads of the shifted row. SLOW path (border threads where the
//             load window would leave [0,NPIX-4]): per-element scalar loads
//             at clamp(qp+e) — for VALID elements qp+e is provably in
//             [0,NPIX), so the clamp never corrupts a valid element (r12's
//             bug was clamping the VECTOR base, shifting valid lanes' data).
//             s = sum_c (fp-fq)^2 — identical math to the proven scalar prep.
//   [432,496) transpose W1,W2 -> [tap][o][c].
//   [496,560) transpose x -> xT[pix][c].
// ---------------------------------------------------------------------------
__global__ __launch_bounds__(256) void prep4_kernel(
    const float* __restrict__ x, const float* __restrict__ f,
    const float* __restrict__ W1, const float* __restrict__ W2,
    float* __restrict__ xT, float* __restrict__ kbuf,
    unsigned char* __restrict__ mask32,
    float* __restrict__ W1t, float* __restrict__ W2t)
{
    const int bid = blockIdx.x;
    const int tid = threadIdx.x;

    if (bid < 432) {                           // ---- correlation prep
        const int tid4 = bid * 256 + tid;      // [0, 27*4096)
        const int iz = tid4 >> 12;             // 0..26
        const int pix0 = (tid4 & 4095) << 2;   // 4-aligned pixel
        const int i = iz / 3, z = iz - 3 * i;
        const int hh = pix0 >> 7, ww0 = pix0 & 127;
        const int di = 2 * i - 8;
        const bool vh = (unsigned)(hh + di) < HH;

        int dj[3], qp[3];
        bool fast[3];
#pragma unroll
        for (int t = 0; t < 3; ++t) {
            int j = 3 * z + t;
            dj[t] = 2 * j - 8;
            qp[t] = pix0 + di * WW + dj[t];    // even -> 8B-aligned when fast
            fast[t] = vh && (qp[t] >= 0) && (qp[t] <= NPIX - 4);
        }
        // slow-path per-element clamped addresses (valid elems: qp+e already
        // in [0,NPIX), so clamp never corrupts a valid element)
        int sa[3][4];
#pragma unroll
        for (int t = 0; t < 3; ++t)
#pragma unroll
            for (int e = 0; e < 4; ++e) {
                int a = qp[t] + e;
                sa[t][e] = a < 0 ? 0 : (a > NPIX - 1 ? NPIX - 1 : a);
            }

        float acc[3][4];
#pragma unroll
        for (int t = 0; t < 3; ++t)
#pragma unroll
            for (int e = 0; e < 4; ++e) acc[t][e] = 0.f;

        for (int c = 0; c < NC; ++c) {
            const float* fr = f + c * NPIX;
            float4 fp = *(const float4*)(fr + pix0);
#pragma unroll
            for (int t = 0; t < 3; ++t) {
                float v0, v1, v2, v3;
                if (fast[t]) {
                    float2 qa = *(const float2*)(fr + qp[t]);
                    float2 qc = *(const float2*)(fr + qp[t] + 2);
                    v0 = qa.x; v1 = qa.y; v2 = qc.x; v3 = qc.y;
                } else {
                    v0 = fr[sa[t][0]]; v1 = fr[sa[t][1]];
                    v2 = fr[sa[t][2]]; v3 = fr[sa[t][3]];
                }
                float d0 = fp.x - v0, d1 = fp.y - v1;
                float d2 = fp.z - v2, d3 = fp.w - v3;
                acc[t][0] = fmaf(d0, d0, acc[t][0]);
                acc[t][1] = fmaf(d1, d1, acc[t][1]);
                acc[t][2] = fmaf(d2, d2, acc[t][2]);
                acc[t][3] = fmaf(d3, d3, acc[t][3]);
            }
        }

        unsigned mb0 = 0, mb1 = 0, mb2 = 0, mb3 = 0;
#pragma unroll
        for (int t = 0; t < 3; ++t) {
            int j = 3 * z + t;
            int T = i * KS + j;
            float4 kv4;
#pragma unroll
            for (int e = 0; e < 4; ++e) {
                bool valid = vh && ((unsigned)(ww0 + e + dj[t]) < WW);
                float s = acc[t][e];
                // OOB taps contribute exactly 0 (x zero-padded) -> drop.
                bool live = valid && (s <= SMAX) && (T != 40);
                unsigned bit = live ? (1u << t) : 0u;
                if (e == 0) mb0 |= bit;
                else if (e == 1) mb1 |= bit;
                else if (e == 2) mb2 |= bit;
                else mb3 |= bit;
                float sv = live ? s : 1e30f;   // exp -> 0 for dead (unread)
                float kv = __expf(-0.5f * sv);
                if (e == 0) kv4.x = kv;
                else if (e == 1) kv4.y = kv;
                else if (e == 2) kv4.z = kv;
                else kv4.w = kv;
            }
            *(float4*)(kbuf + T * NPIX + pix0) = kv4;   // 16B aligned
        }
        mask32[(size_t)(pix0 + 0) * 32 + iz] = (unsigned char)mb0;
        mask32[(size_t)(pix0 + 1) * 32 + iz] = (unsigned char)mb1;
        mask32[(size_t)(pix0 + 2) * 32 + iz] = (unsigned char)mb2;
        mask32[(size_t)(pix0 + 3) * 32 + iz] = (unsigned char)mb3;
        return;
    }

    if (bid < 496) {                           // ---- W transpose
        for (int t = (bid - 432) * 256 + tid; t < NW; t += 64 * 256) {
            int o = t / (NC * TAPS);
            int r = t - o * (NC * TAPS);
            int c = r / TAPS;
            int tap = r - c * TAPS;
            int d = (tap * NO + o) * NC + c;
            W1t[d] = W1[t];
            W2t[d] = W2[t];
        }
        return;
    }

    // ---- [496,560): x transpose -> xT[pix][c]
    for (int idx = (bid - 496) * 256 + tid; idx < NPIX * NC; idx += 64 * 256) {
        int p = idx >> 5, c = idx & 31;
        xT[idx] = x[c * NPIX + p];             // writes fully coalesced
    }
}

// ---------------------------------------------------------------------------
// D2 (fused2): BOTH layers, one WAVE per output pixel (r10-proven, 44.9 us;
// held as the D2 floor — r7/r8/r11 restructures all land 44-46 us).
// lane=(half,o); channel sums half-split, combined by one __shfl_xor(.,32);
// h vector published through per-wave LDS slot (same-wave ds ordering).
// Sole writer per (p,o): plain stores, no atomics, no pre-zeroing.
// ---------------------------------------------------------------------------
__global__ __launch_bounds__(256) void fused2_kernel(
    const float* __restrict__ xT, const float* __restrict__ kbuf,
    const unsigned char* __restrict__ mask32,
    const float* __restrict__ W1t, const float* __restrict__ W2t,
    const float* __restrict__ b1, const float* __restrict__ b2,
    float* __restrict__ out)
{
    const int wv = threadIdx.x >> 6;           // wave in block, 0..3
    const int lane = threadIdx.x & 63;
    const int half = lane >> 5;                // 0/1
    const int o = lane & 31;                   // output channel
    const int c0 = half * 16;                  // this lane's channel window
    const int p = blockIdx.x * 4 + wv;
    __shared__ float hlds[4][NC];

    const float b1o = b1[o];

#define DOT16(WROW, XROW, RES) do {                                        \
        const float4* wq_ = (const float4*)((WROW) + c0);                  \
        const float4* xq_ = (const float4*)((XROW) + c0);                  \
        float r0_ = 0.f, r1_ = 0.f, r2_ = 0.f, r3_ = 0.f;                  \
        _Pragma("unroll")                                                  \
        for (int k_ = 0; k_ < 4; ++k_) {                                   \
            float4 w4_ = wq_[k_], x4_ = xq_[k_];                           \
            r0_ = fmaf(w4_.x, x4_.x, r0_);                                 \
            r1_ = fmaf(w4_.y, x4_.y, r1_);                                 \
            r2_ = fmaf(w4_.z, x4_.z, r2_);                                 \
            r3_ = fmaf(w4_.w, x4_.w, r3_);                                 \
        }                                                                  \
        RES = (r0_ + r1_) + (r2_ + r3_);                                   \
    } while (0)

    unsigned long long A0; unsigned A1;        // p's live mask (kept)
    BUILD_MASK32(p, A0, A1);
    unsigned long long A0s = A0; unsigned A1s = A1;  // consumed by outer walk

    float acc = 0.f;                           // half-partial of output dot
    int first = 1;
    for (;;) {
        int Tq, q; float kvq;
        if (first)      { Tq = 40; q = p; kvq = 1.0f; }
        else if (A0s) {
            Tq = __builtin_ctzll(A0s); A0s &= A0s - 1;
            int ii = Tq / KS, jj = Tq - KS * ii;
            q = p + (ii * DIL - PAD) * WW + (jj * DIL - PAD);
            kvq = kbuf[Tq * NPIX + p];
        } else if (A1s) {
            Tq = 64 + __builtin_ctz(A1s); A1s &= A1s - 1;
            int ii = Tq / KS, jj = Tq - KS * ii;
            q = p + (ii * DIL - PAD) * WW + (jj * DIL - PAD);
            kvq = kbuf[Tq * NPIX + p];
        } else break;

        // ---- h(q): half-partial over this lane's 16 channels
        unsigned long long B0; unsigned B1;
        if (first) { B0 = A0; B1 = A1; }       // q == p: reuse mask
        else BUILD_MASK32(q, B0, B1);

        float hpart;
        DOT16(W1t + (40 * NO + o) * NC, xT + q * NC, hpart);   // center of q
        while (B0) {
            int T2 = __builtin_ctzll(B0); B0 &= B0 - 1;
            int i2 = T2 / KS, j2 = T2 - KS * i2;
            int q2 = q + (i2 * DIL - PAD) * WW + (j2 * DIL - PAD);
            float kv2 = kbuf[T2 * NPIX + q];
            float d; DOT16(W1t + (T2 * NO + o) * NC, xT + q2 * NC, d);
            hpart = fmaf(kv2, d, hpart);
        }
        while (B1) {
            int T2 = 64 + __builtin_ctz(B1); B1 &= B1 - 1;
            int i2 = T2 / KS, j2 = T2 - KS * i2;
            int q2 = q + (i2 * DIL - PAD) * WW + (j2 * DIL - PAD);
            float kv2 = kbuf[T2 * NPIX + q];
            float d; DOT16(W1t + (T2 * NO + o) * NC, xT + q2 * NC, d);
            hpart = fmaf(kv2, d, hpart);
        }
        float hfull = hpart + __shfl_xor(hpart, 32);  // combine halves
        hfull += b1o;                                  // h(q)[o], all 64 lanes
        if (half == 0) hlds[wv][o] = hfull;            // publish h vector
        // same-wave ds_write -> ds_read (r8/r10-proven ordering)
        float wsdot;
        DOT16(W2t + (Tq * NO + o) * NC, &hlds[wv][0], wsdot);
        acc = fmaf(kvq, wsdot, acc);
        first = 0;
    }
#undef DOT16

    float accf = acc + __shfl_xor(acc, 32);
    if (half == 0) out[o * NPIX + p] = accf + b2[o];
}

// ===========================================================================
// Fallback path A (round-5 proven, 126.9 us): 4 classic dispatches.
// ===========================================================================
__global__ __launch_bounds__(64) void zero_cnt_kernel(unsigned* __restrict__ cnt)
{
    if (threadIdx.x == 0) *cnt = 0u;
}

__device__ __forceinline__ void sparse_body(
    const float* __restrict__ in, const float* __restrict__ Wt,
    const unsigned* __restrict__ cnt, const uint2* __restrict__ list,
    float* __restrict__ out, unsigned gid, unsigned stride)
{
    unsigned n = *cnt;
    if (n > CAP) n = CAP;
    const unsigned total = n * 32u;
    for (unsigned it = gid; it < total; it += stride) {
        unsigned e = it >> 5;
        int o = (int)(it & 31u);
        uint2 me = list[e];
        int pix = (int)(me.x & 16383u);
        int T = (int)(me.x >> 14);
        float kv = __uint_as_float(me.y);
        int ii = T / KS, jj = T - KS * ii;
        int q = pix + (ii * DIL - PAD) * WW + (jj * DIL - PAD);
        const float4* __restrict__ wp =
            (const float4*)(Wt + (T * NO + o) * NC);
        float t0 = 0.f, t1 = 0.f, t2 = 0.f, t3 = 0.f;
#pragma unroll
        for (int c4 = 0; c4 < 8; ++c4) {
            float4 w4 = wp[c4];
            t0 = fmaf(in[(4 * c4 + 0) * NPIX + q], w4.x, t0);
            t1 = fmaf(in[(4 * c4 + 1) * NPIX + q], w4.y, t1);
            t2 = fmaf(in[(4 * c4 + 2) * NPIX + q], w4.z, t2);
            t3 = fmaf(in[(4 * c4 + 3) * NPIX + q], w4.w, t3);
        }
        atomicAdd(&out[o * NPIX + pix], kv * ((t0 + t1) + (t2 + t3)));
    }
}

__global__ __launch_bounds__(256) void front_kernel(
    const float* __restrict__ x, const float* __restrict__ f,
    const float* __restrict__ W1, const float* __restrict__ W2,
    const float* __restrict__ b1,
    float* __restrict__ h, unsigned* __restrict__ cnt,
    uint2* __restrict__ list, float* __restrict__ W1t,
    float* __restrict__ W2t, float* __restrict__ outz)
{
    const int y = blockIdx.y;
    const int tid = threadIdx.x;

    if (y < 41) {
        const int pix = blockIdx.x * 256 + tid;
        const int hh = pix >> 7, ww = pix & (WW - 1);
        float fc[NC];
#pragma unroll
        for (int c = 0; c < NC; ++c) fc[c] = f[c * NPIX + pix];
#pragma unroll
        for (int u = 0; u < 2; ++u) {
            int T = 2 * y + u;
            if (T >= TAPS || T == 40) continue;
            int ii = T / KS, jj = T - KS * ii;
            int qh = hh + ii * DIL - PAD;
            int qw = ww + jj * DIL - PAD;
            bool valid = ((unsigned)qh < HH) & ((unsigned)qw < WW);
            int q = valid ? (qh * WW + qw) : pix;
            float s0 = 0.f, s1 = 0.f, s2 = 0.f, s3 = 0.f;
#pragma unroll
            for (int c4 = 0; c4 < 8; ++c4) {
                float d0 = f[(4 * c4 + 0) * NPIX + q] - fc[4 * c4 + 0];
                float d1 = f[(4 * c4 + 1) * NPIX + q] - fc[4 * c4 + 1];
                float d2 = f[(4 * c4 + 2) * NPIX + q] - fc[4 * c4 + 2];
                float d3 = f[(4 * c4 + 3) * NPIX + q] - fc[4 * c4 + 3];
                s0 = fmaf(d0, d0, s0); s1 = fmaf(d1, d1, s1);
                s2 = fmaf(d2, d2, s2); s3 = fmaf(d3, d3, s3);
            }
            float s = (s0 + s1) + (s2 + s3);
            if (valid && (s <= SMAX)) {
                unsigned idx = atomicAdd(cnt, 1u);
                if (idx < CAP)
                    list[idx] = make_uint2(
                        (unsigned)pix | ((unsigned)T << 14),
                        __float_as_uint(__expf(-0.5f * s)));
            }
        }
        return;
    }

    if (y < 49) {
        const int o0 = (y - 41) * 4;
        __shared__ float wsm[4 * NC];
        if (tid < 128) {
            int o = tid >> 5, c = tid & 31;
            wsm[tid] = W1[((o0 + o) * NC + c) * TAPS + 40];
        }
        __syncthreads();
        const int pix = blockIdx.x * 256 + tid;
        float x0[NC];
#pragma unroll
        for (int c = 0; c < NC; ++c) x0[c] = x[c * NPIX + pix];
        float a0 = 0.f, a1 = 0.f, a2 = 0.f, a3 = 0.f;
#pragma unroll
        for (int c = 0; c < NC; ++c) {
            float xv = x0[c];
            a0 = fmaf(xv, wsm[0 * NC + c], a0);
            a1 = fmaf(xv, wsm[1 * NC + c], a1);
            a2 = fmaf(xv, wsm[2 * NC + c], a2);
            a3 = fmaf(xv, wsm[3 * NC + c], a3);
        }
        h[(o0 + 0) * NPIX + pix] = a0 + b1[o0 + 0];
        h[(o0 + 1) * NPIX + pix] = a1 + b1[o0 + 1];
        h[(o0 + 2) * NPIX + pix] = a2 + b1[o0 + 2];
        h[(o0 + 3) * NPIX + pix] = a3 + b1[o0 + 3];
        return;
    }

    if (y == 49) {
        float4 z = make_float4(0.f, 0.f, 0.f, 0.f);
        for (int t = blockIdx.x * 256 + tid; t < (NO * NPIX) / 4; t += 64 * 256)
            ((float4*)outz)[t] = z;
        return;
    }

    for (int t = blockIdx.x * 256 + tid; t < NW; t += 64 * 256) {
        int o = t / (NC * TAPS);
        int r = t - o * (NC * TAPS);
        int c = r / TAPS;
        int tap = r - c * TAPS;
        int d = (tap * NO + o) * NC + c;
        W1t[d] = W1[t];
        W2t[d] = W2[t];
    }
}

__global__ __launch_bounds__(256) void sparse1_kernel(
    const float* __restrict__ x, const float* __restrict__ W1t,
    const unsigned* __restrict__ cnt, const uint2* __restrict__ list,
    float* __restrict__ h)
{
    sparse_body(x, W1t, cnt, list, h,
                blockIdx.x * 256 + threadIdx.x, gridDim.x * 256);
}

__global__ __launch_bounds__(256) void back_kernel(
    const float* __restrict__ h, const float* __restrict__ W2,
    const float* __restrict__ W2t, const float* __restrict__ b2,
    const unsigned* __restrict__ cnt, const uint2* __restrict__ list,
    float* __restrict__ out)
{
    const int y = blockIdx.y;
    const int tid = threadIdx.x;
    if (y < 8) {
        const int o0 = y * 4;
        __shared__ float wsm[4 * NC];
        if (tid < 128) {
            int o = tid >> 5, c = tid & 31;
            wsm[tid] = W2[((o0 + o) * NC + c) * TAPS + 40];
        }
        __syncthreads();
        const int pix = blockIdx.x * 256 + tid;
        float h0[NC];
#pragma unroll
        for (int c = 0; c < NC; ++c) h0[c] = h[c * NPIX + pix];
        float a0 = 0.f, a1 = 0.f, a2 = 0.f, a3 = 0.f;
#pragma unroll
        for (int c = 0; c < NC; ++c) {
            float hv = h0[c];
            a0 = fmaf(hv, wsm[0 * NC + c], a0);
            a1 = fmaf(hv, wsm[1 * NC + c], a1);
            a2 = fmaf(hv, wsm[2 * NC + c], a2);
            a3 = fmaf(hv, wsm[3 * NC + c], a3);
        }
        atomicAdd(&out[(o0 + 0) * NPIX + pix], a0 + b2[o0 + 0]);
        atomicAdd(&out[(o0 + 1) * NPIX + pix], a1 + b2[o0 + 1]);
        atomicAdd(&out[(o0 + 2) * NPIX + pix], a2 + b2[o0 + 2]);
        atomicAdd(&out[(o0 + 3) * NPIX + pix], a3 + b2[o0 + 3]);
        return;
    }
    sparse_body(h, W2t, cnt, list, out,
                blockIdx.x * 256 + tid, 64 * 256);
}

// ===========================================================================
// Fallback path B (tiny ws): fused per-layer, original W layout.
// ===========================================================================
#define CHUNK 27
#define NCHUNK 3
#define KMIN 1e-6f
__global__ __launch_bounds__(256) void pac_layer_fuse(
    const float* __restrict__ in, const float* __restrict__ f,
    const float* __restrict__ Wt, const float* __restrict__ bias,
    float* __restrict__ out)
{
    __shared__ float wl[NC * CHUNK * 8];
    const int og = blockIdx.y;
    const int pix = blockIdx.x * 256 + threadIdx.x;
    const int h = pix >> 7, w = pix & (WW - 1);
    float acc[8];
#pragma unroll
    for (int i = 0; i < 8; ++i) acc[i] = 0.f;
    float fc[NC];
#pragma unroll
    for (int c = 0; c < NC; ++c) fc[c] = f[c * NPIX + pix];
    for (int ch = 0; ch < NCHUNK; ++ch) {
        __syncthreads();
        for (int idx = threadIdx.x; idx < NC * CHUNK * 8; idx += 256) {
            int t = idx % CHUNK;
            int c = (idx / CHUNK) % NC;
            int o = idx / (CHUNK * NC);
            wl[(c * CHUNK + t) * 8 + o] =
                Wt[(og * 8 + o) * (NC * TAPS) + c * TAPS + ch * CHUNK + t];
        }
        __syncthreads();
        for (int t = 0; t < CHUNK; ++t) {
            int tap = ch * CHUNK + t;
            int qh = h + (tap / KS) * DIL - PAD;
            int qw = w + (tap % KS) * DIL - PAD;
            bool valid = ((unsigned)qh < HH) & ((unsigned)qw < WW);
            int q = qh * WW + qw;
            float s = 0.f;
#pragma unroll
            for (int c = 0; c < NC; ++c) {
                float fn = valid ? f[c * NPIX + q] : 0.f;
                float d = fn - fc[c];
                s = fmaf(d, d, s);
            }
            float kv = __expf(-0.5f * s);
            if (__all((kv < KMIN) | (!valid))) continue;
            const float* wpp = &wl[t * 8];
#pragma unroll 8
            for (int c = 0; c < NC; ++c) {
                float v = valid ? in[c * NPIX + q] : 0.f;
                v *= kv;
#pragma unroll
                for (int o = 0; o < 8; ++o)
                    acc[o] = fmaf(v, wpp[c * CHUNK * 8 + o], acc[o]);
            }
        }
    }
#pragma unroll
    for (int o = 0; o < 8; ++o)
        out[(og * 8 + o) * NPIX + pix] = acc[o] + bias[og * 8 + o];
}

// ---------------------------------------------------------------------------
extern "C" void kernel_launch(void* const* d_in, const int* in_sizes, int n_in,
                              void* d_out, int out_size, void* d_ws, size_t ws_size,
                              hipStream_t stream)
{
    (void)in_sizes; (void)n_in; (void)out_size;
    const float* x  = (const float*)d_in[0];
    const float* f  = (const float*)d_in[1];
    const float* W1 = (const float*)d_in[2];
    const float* b1 = (const float*)d_in[3];
    const float* W2 = (const float*)d_in[4];
    const float* b2 = (const float*)d_in[5];
    float* out = (float*)d_out;

    float* ws = (float*)d_ws;
    // main (2-dispatch) layout
    float* xT   = ws;                                   // NPIX*NC
    float* kbuf = xT + NPIX * NC;                       // TAPS*NPIX
    float* W1t  = kbuf + TAPS * NPIX;                   // NW
    float* W2t  = W1t + NW;                             // NW
    unsigned char* mask32 = (unsigned char*)(W2t + NW); // NPIX*32 B
    const size_t need_main =
        (size_t)(NPIX * NC + TAPS * NPIX + 2 * NW) * 4
        + (size_t)NPIX * 32;
    // fallback-A layout
    float* hA   = ws;
    float* W1tA = ws + NO * NPIX;
    float* W2tA = W1tA + NW;
    unsigned* cnt = (unsigned*)(W2tA + NW);
    uint2* list = (uint2*)(cnt + 16);
    const size_t need_fb =
        (size_t)(NO * NPIX + 2 * NW + 16) * 4 + (size_t)CAP * 8;

    if (ws_size >= need_main) {
        prep4_kernel<<<dim3(560), 256, 0, stream>>>(
            x, f, W1, W2, xT, kbuf, mask32, W1t, W2t);
        fused2_kernel<<<dim3(NPIX / 4), 256, 0, stream>>>(
            xT, kbuf, mask32, W1t, W2t, b1, b2, out);
    } else if (ws_size >= need_fb) {
        zero_cnt_kernel<<<dim3(1), 64, 0, stream>>>(cnt);
        front_kernel<<<dim3(64, 51), 256, 0, stream>>>(
            x, f, W1, W2, b1, hA, cnt, list, W1tA, W2tA, out);
        sparse1_kernel<<<dim3(128), 256, 0, stream>>>(x, W1tA, cnt, list, hA);
        back_kernel<<<dim3(64, 9), 256, 0, stream>>>(
            hA, W2, W2tA, b2, cnt, list, out);
    } else {
        float* hbuf = ws;
        pac_layer_fuse<<<dim3(64, 4), 256, 0, stream>>>(x, f, W1, b1, hbuf);
        pac_layer_fuse<<<dim3(64, 4), 256, 0, stream>>>(hbuf, f, W2, b2, out);
    }
}

// Round 14
// 137.792 us; speedup vs baseline: 1.1223x; 1.1223x over previous
//
#include <hip/hip_runtime.h>

#define HH 128
#define WW 128
#define NPIX 16384
#define NC 32
#define NO 32
#define KS 9
#define TAPS 81
#define DIL 2
#define PAD 8
#define SMAX 27.6310211159f   // s <= SMAX <=> exp(-0.5 s) >= 1e-6; dropped-tap bound ~1.4e-5 << tol
#define NW (NO * NC * TAPS)   // 82944
#define CAP 262144            // fallback-A list capacity

// ---------------------------------------------------------------------------
// Per-pixel mask record: 32 bytes, byte iz = i*3+z holds the 3-bit live mask
// for taps j in {3z,3z+1,3z+2} of row i (bytes 27..31 never read).
// Written byte-owned by prep threads (no atomics), read as 2x uint4.
// ---------------------------------------------------------------------------
#define BUILD_MASK32(P, M0, M1) do {                                        \
        const uint4* mp_ = (const uint4*)(mask32 + (size_t)(P) * 32);       \
        uint4 ma_ = mp_[0], mb_ = mp_[1];                                   \
        unsigned w_[8] = { ma_.x, ma_.y, ma_.z, ma_.w,                      \
                           mb_.x, mb_.y, mb_.z, mb_.w };                    \
        M0 = 0ull; M1 = 0u;                                                 \
        unsigned m9_[9];                                                    \
        _Pragma("unroll")                                                   \
        for (int i_ = 0; i_ < 9; ++i_) {                                    \
            int k0_ = 3 * i_, k1_ = 3 * i_ + 1, k2_ = 3 * i_ + 2;           \
            unsigned b0_ = (w_[k0_ >> 2] >> ((k0_ & 3) * 8)) & 7u;          \
            unsigned b1_ = (w_[k1_ >> 2] >> ((k1_ & 3) * 8)) & 7u;          \
            unsigned b2_ = (w_[k2_ >> 2] >> ((k2_ & 3) * 8)) & 7u;          \
            m9_[i_] = b0_ | (b1_ << 3) | (b2_ << 6);                        \
        }                                                                   \
        _Pragma("unroll")                                                   \
        for (int i_ = 0; i_ < 7; ++i_)                                      \
            M0 |= (unsigned long long)m9_[i_] << (9 * i_);                  \
        M0 |= (unsigned long long)(m9_[7] & 1u) << 63;                      \
        M1 = (m9_[7] >> 1) | (m9_[8] << 8);                                 \
    } while (0)

// ---------------------------------------------------------------------------
// D1 (prep5): r13's shift-correlation prep (PASSED correctness) with the TLP
// restored: the 32-channel loop is split 4-ways across ADJACENT LANES
// (cgrp = gid&3 owns channels 8*cgrp..8*cgrp+7). 1728 prep blocks = prep3's
// occupancy (6.75 waves/SIMD; r13's prep4 had 432 blocks = 1.7 waves/SIMD and
// was latency-bound at 54 us, 15% occupancy). Per-thread chain: 56 loads.
// Partials combine with two __shfl_xor (1,2); cgrp==0 lane runs the r13
// epilogue verbatim (byte-owned masks + float4 kbuf, unconditional).
// Roles by blockIdx.x:
//   [0,1728)    prep (channel-split shift-correlation)
//   [1728,1792) transpose W1,W2 -> [tap][o][c]
//   [1792,1856) transpose x -> xT[pix][c]
// ---------------------------------------------------------------------------
__global__ __launch_bounds__(256) void prep5_kernel(
    const float* __restrict__ x, const float* __restrict__ f,
    const float* __restrict__ W1, const float* __restrict__ W2,
    float* __restrict__ xT, float* __restrict__ kbuf,
    unsigned char* __restrict__ mask32,
    float* __restrict__ W1t, float* __restrict__ W2t)
{
    const int bid = blockIdx.x;
    const int tid = threadIdx.x;

    if (bid < 1728) {                          // ---- correlation prep
        const int gid = bid * 256 + tid;       // [0, 27*4096*4)
        const int cgrp = gid & 3;              // channel group (8 channels)
        const int g = gid >> 2;                // [0, 27*4096)
        const int iz = g >> 12;                // 0..26
        const int pix0 = (g & 4095) << 2;      // 4-aligned pixel
        const int i = iz / 3, z = iz - 3 * i;
        const int hh = pix0 >> 7, ww0 = pix0 & 127;
        const int di = 2 * i - 8;
        const bool vh = (unsigned)(hh + di) < HH;

        int dj[3], qp[3];
        bool fast[3];
#pragma unroll
        for (int t = 0; t < 3; ++t) {
            int j = 3 * z + t;
            dj[t] = 2 * j - 8;
            qp[t] = pix0 + di * WW + dj[t];    // even -> 8B-aligned when fast
            fast[t] = vh && (qp[t] >= 0) && (qp[t] <= NPIX - 4);
        }
        // slow-path per-element clamped addresses (valid elems: qp+e already
        // in [0,NPIX), so clamp never corrupts a valid element) [r13-proven]
        int sa[3][4];
#pragma unroll
        for (int t = 0; t < 3; ++t)
#pragma unroll
            for (int e = 0; e < 4; ++e) {
                int a = qp[t] + e;
                sa[t][e] = a < 0 ? 0 : (a > NPIX - 1 ? NPIX - 1 : a);
            }

        float acc[3][4];
#pragma unroll
        for (int t = 0; t < 3; ++t)
#pragma unroll
            for (int e = 0; e < 4; ++e) acc[t][e] = 0.f;

#pragma unroll
        for (int k = 0; k < 8; ++k) {
            const int c = cgrp * 8 + k;
            const float* fr = f + c * NPIX;
            float4 fp = *(const float4*)(fr + pix0);
#pragma unroll
            for (int t = 0; t < 3; ++t) {
                float v0, v1, v2, v3;
                if (fast[t]) {
                    float2 qa = *(const float2*)(fr + qp[t]);
                    float2 qc = *(const float2*)(fr + qp[t] + 2);
                    v0 = qa.x; v1 = qa.y; v2 = qc.x; v3 = qc.y;
                } else {
                    v0 = fr[sa[t][0]]; v1 = fr[sa[t][1]];
                    v2 = fr[sa[t][2]]; v3 = fr[sa[t][3]];
                }
                float d0 = fp.x - v0, d1 = fp.y - v1;
                float d2 = fp.z - v2, d3 = fp.w - v3;
                acc[t][0] = fmaf(d0, d0, acc[t][0]);
                acc[t][1] = fmaf(d1, d1, acc[t][1]);
                acc[t][2] = fmaf(d2, d2, acc[t][2]);
                acc[t][3] = fmaf(d3, d3, acc[t][3]);
            }
        }

        // combine the 4 channel-group partials within each 4-lane group
#pragma unroll
        for (int t = 0; t < 3; ++t)
#pragma unroll
            for (int e = 0; e < 4; ++e) {
                float v = acc[t][e];
                v += __shfl_xor(v, 1);
                v += __shfl_xor(v, 2);
                acc[t][e] = v;
            }

        if (cgrp == 0) {                       // r13-proven epilogue
            unsigned mb0 = 0, mb1 = 0, mb2 = 0, mb3 = 0;
#pragma unroll
            for (int t = 0; t < 3; ++t) {
                int j = 3 * z + t;
                int T = i * KS + j;
                float4 kv4;
#pragma unroll
                for (int e = 0; e < 4; ++e) {
                    bool valid = vh && ((unsigned)(ww0 + e + dj[t]) < WW);
                    float s = acc[t][e];
                    // OOB taps contribute exactly 0 (x zero-padded) -> drop.
                    bool live = valid && (s <= SMAX) && (T != 40);
                    unsigned bit = live ? (1u << t) : 0u;
                    if (e == 0) mb0 |= bit;
                    else if (e == 1) mb1 |= bit;
                    else if (e == 2) mb2 |= bit;
                    else mb3 |= bit;
                    float sv = live ? s : 1e30f;   // exp -> 0 (unread slots)
                    float kv = __expf(-0.5f * sv);
                    if (e == 0) kv4.x = kv;
                    else if (e == 1) kv4.y = kv;
                    else if (e == 2) kv4.z = kv;
                    else kv4.w = kv;
                }
                *(float4*)(kbuf + T * NPIX + pix0) = kv4;   // 16B aligned
            }
            mask32[(size_t)(pix0 + 0) * 32 + iz] = (unsigned char)mb0;
            mask32[(size_t)(pix0 + 1) * 32 + iz] = (unsigned char)mb1;
            mask32[(size_t)(pix0 + 2) * 32 + iz] = (unsigned char)mb2;
            mask32[(size_t)(pix0 + 3) * 32 + iz] = (unsigned char)mb3;
        }
        return;
    }

    if (bid < 1792) {                          // ---- W transpose
        for (int t = (bid - 1728) * 256 + tid; t < NW; t += 64 * 256) {
            int o = t / (NC * TAPS);
            int r = t - o * (NC * TAPS);
            int c = r / TAPS;
            int tap = r - c * TAPS;
            int d = (tap * NO + o) * NC + c;
            W1t[d] = W1[t];
            W2t[d] = W2[t];
        }
        return;
    }

    // ---- [1792,1856): x transpose -> xT[pix][c]
    for (int idx = (bid - 1792) * 256 + tid; idx < NPIX * NC; idx += 64 * 256) {
        int p = idx >> 5, c = idx & 31;
        xT[idx] = x[c * NPIX + p];             // writes fully coalesced
    }
}

// ---------------------------------------------------------------------------
// D2 (fused2): BOTH layers, one WAVE per output pixel (r10/r13-proven,
// ~45 us; held as the D2 floor — r7/r8/r11 restructures all land 44-46 us).
// lane=(half,o); channel sums half-split, combined by one __shfl_xor(.,32);
// h vector published through per-wave LDS slot (same-wave ds ordering).
// Sole writer per (p,o): plain stores, no atomics, no pre-zeroing.
// ---------------------------------------------------------------------------
__global__ __launch_bounds__(256) void fused2_kernel(
    const float* __restrict__ xT, const float* __restrict__ kbuf,
    const unsigned char* __restrict__ mask32,
    const float* __restrict__ W1t, const float* __restrict__ W2t,
    const float* __restrict__ b1, const float* __restrict__ b2,
    float* __restrict__ out)
{
    const int wv = threadIdx.x >> 6;           // wave in block, 0..3
    const int lane = threadIdx.x & 63;
    const int half = lane >> 5;                // 0/1
    const int o = lane & 31;                   // output channel
    const int c0 = half * 16;                  // this lane's channel window
    const int p = blockIdx.x * 4 + wv;
    __shared__ float hlds[4][NC];

    const float b1o = b1[o];

#define DOT16(WROW, XROW, RES) do {                                        \
        const float4* wq_ = (const float4*)((WROW) + c0);                  \
        const float4* xq_ = (const float4*)((XROW) + c0);                  \
        float r0_ = 0.f, r1_ = 0.f, r2_ = 0.f, r3_ = 0.f;                  \
        _Pragma("unroll")                                                  \
        for (int k_ = 0; k_ < 4; ++k_) {                                   \
            float4 w4_ = wq_[k_], x4_ = xq_[k_];                           \
            r0_ = fmaf(w4_.x, x4_.x, r0_);                                 \
            r1_ = fmaf(w4_.y, x4_.y, r1_);                                 \
            r2_ = fmaf(w4_.z, x4_.z, r2_);                                 \
            r3_ = fmaf(w4_.w, x4_.w, r3_);                                 \
        }                                                                  \
        RES = (r0_ + r1_) + (r2_ + r3_);                                   \
    } while (0)

    unsigned long long A0; unsigned A1;        // p's live mask (kept)
    BUILD_MASK32(p, A0, A1);
    unsigned long long A0s = A0; unsigned A1s = A1;  // consumed by outer walk

    float acc = 0.f;                           // half-partial of output dot
    int first = 1;
    for (;;) {
        int Tq, q; float kvq;
        if (first)      { Tq = 40; q = p; kvq = 1.0f; }
        else if (A0s) {
            Tq = __builtin_ctzll(A0s); A0s &= A0s - 1;
            int ii = Tq / KS, jj = Tq - KS * ii;
            q = p + (ii * DIL - PAD) * WW + (jj * DIL - PAD);
            kvq = kbuf[Tq * NPIX + p];
        } else if (A1s) {
            Tq = 64 + __builtin_ctz(A1s); A1s &= A1s - 1;
            int ii = Tq / KS, jj = Tq - KS * ii;
            q = p + (ii * DIL - PAD) * WW + (jj * DIL - PAD);
            kvq = kbuf[Tq * NPIX + p];
        } else break;

        // ---- h(q): half-partial over this lane's 16 channels
        unsigned long long B0; unsigned B1;
        if (first) { B0 = A0; B1 = A1; }       // q == p: reuse mask
        else BUILD_MASK32(q, B0, B1);

        float hpart;
        DOT16(W1t + (40 * NO + o) * NC, xT + q * NC, hpart);   // center of q
        while (B0) {
            int T2 = __builtin_ctzll(B0); B0 &= B0 - 1;
            int i2 = T2 / KS, j2 = T2 - KS * i2;
            int q2 = q + (i2 * DIL - PAD) * WW + (j2 * DIL - PAD);
            float kv2 = kbuf[T2 * NPIX + q];
            float d; DOT16(W1t + (T2 * NO + o) * NC, xT + q2 * NC, d);
            hpart = fmaf(kv2, d, hpart);
        }
        while (B1) {
            int T2 = 64 + __builtin_ctz(B1); B1 &= B1 - 1;
            int i2 = T2 / KS, j2 = T2 - KS * i2;
            int q2 = q + (i2 * DIL - PAD) * WW + (j2 * DIL - PAD);
            float kv2 = kbuf[T2 * NPIX + q];
            float d; DOT16(W1t + (T2 * NO + o) * NC, xT + q2 * NC, d);
            hpart = fmaf(kv2, d, hpart);
        }
        float hfull = hpart + __shfl_xor(hpart, 32);  // combine halves
        hfull += b1o;                                  // h(q)[o], all 64 lanes
        if (half == 0) hlds[wv][o] = hfull;            // publish h vector
        // same-wave ds_write -> ds_read (r8/r10-proven ordering)
        float wsdot;
        DOT16(W2t + (Tq * NO + o) * NC, &hlds[wv][0], wsdot);
        acc = fmaf(kvq, wsdot, acc);
        first = 0;
    }
#undef DOT16

    float accf = acc + __shfl_xor(acc, 32);
    if (half == 0) out[o * NPIX + p] = accf + b2[o];
}

// ===========================================================================
// Fallback path A (round-5 proven, 126.9 us): 4 classic dispatches.
// ===========================================================================
__global__ __launch_bounds__(64) void zero_cnt_kernel(unsigned* __restrict__ cnt)
{
    if (threadIdx.x == 0) *cnt = 0u;
}

__device__ __forceinline__ void sparse_body(
    const float* __restrict__ in, const float* __restrict__ Wt,
    const unsigned* __restrict__ cnt, const uint2* __restrict__ list,
    float* __restrict__ out, unsigned gid, unsigned stride)
{
    unsigned n = *cnt;
    if (n > CAP) n = CAP;
    const unsigned total = n * 32u;
    for (unsigned it = gid; it < total; it += stride) {
        unsigned e = it >> 5;
        int o = (int)(it & 31u);
        uint2 me = list[e];
        int pix = (int)(me.x & 16383u);
        int T = (int)(me.x >> 14);
        float kv = __uint_as_float(me.y);
        int ii = T / KS, jj = T - KS * ii;
        int q = pix + (ii * DIL - PAD) * WW + (jj * DIL - PAD);
        const float4* __restrict__ wp =
            (const float4*)(Wt + (T * NO + o) * NC);
        float t0 = 0.f, t1 = 0.f, t2 = 0.f, t3 = 0.f;
#pragma unroll
        for (int c4 = 0; c4 < 8; ++c4) {
            float4 w4 = wp[c4];
            t0 = fmaf(in[(4 * c4 + 0) * NPIX + q], w4.x, t0);
            t1 = fmaf(in[(4 * c4 + 1) * NPIX + q], w4.y, t1);
            t2 = fmaf(in[(4 * c4 + 2) * NPIX + q], w4.z, t2);
            t3 = fmaf(in[(4 * c4 + 3) * NPIX + q], w4.w, t3);
        }
        atomicAdd(&out[o * NPIX + pix], kv * ((t0 + t1) + (t2 + t3)));
    }
}

__global__ __launch_bounds__(256) void front_kernel(
    const float* __restrict__ x, const float* __restrict__ f,
    const float* __restrict__ W1, const float* __restrict__ W2,
    const float* __restrict__ b1,
    float* __restrict__ h, unsigned* __restrict__ cnt,
    uint2* __restrict__ list, float* __restrict__ W1t,
    float* __restrict__ W2t, float* __restrict__ outz)
{
    const int y = blockIdx.y;
    const int tid = threadIdx.x;

    if (y < 41) {
        const int pix = blockIdx.x * 256 + tid;
        const int hh = pix >> 7, ww = pix & (WW - 1);
        float fc[NC];
#pragma unroll
        for (int c = 0; c < NC; ++c) fc[c] = f[c * NPIX + pix];
#pragma unroll
        for (int u = 0; u < 2; ++u) {
            int T = 2 * y + u;
            if (T >= TAPS || T == 40) continue;
            int ii = T / KS, jj = T - KS * ii;
            int qh = hh + ii * DIL - PAD;
            int qw = ww + jj * DIL - PAD;
            bool valid = ((unsigned)qh < HH) & ((unsigned)qw < WW);
            int q = valid ? (qh * WW + qw) : pix;
            float s0 = 0.f, s1 = 0.f, s2 = 0.f, s3 = 0.f;
#pragma unroll
            for (int c4 = 0; c4 < 8; ++c4) {
                float d0 = f[(4 * c4 + 0) * NPIX + q] - fc[4 * c4 + 0];
                float d1 = f[(4 * c4 + 1) * NPIX + q] - fc[4 * c4 + 1];
                float d2 = f[(4 * c4 + 2) * NPIX + q] - fc[4 * c4 + 2];
                float d3 = f[(4 * c4 + 3) * NPIX + q] - fc[4 * c4 + 3];
                s0 = fmaf(d0, d0, s0); s1 = fmaf(d1, d1, s1);
                s2 = fmaf(d2, d2, s2); s3 = fmaf(d3, d3, s3);
            }
            float s = (s0 + s1) + (s2 + s3);
            if (valid && (s <= SMAX)) {
                unsigned idx = atomicAdd(cnt, 1u);
                if (idx < CAP)
                    list[idx] = make_uint2(
                        (unsigned)pix | ((unsigned)T << 14),
                        __float_as_uint(__expf(-0.5f * s)));
            }
        }
        return;
    }

    if (y < 49) {
        const int o0 = (y - 41) * 4;
        __shared__ float wsm[4 * NC];
        if (tid < 128) {
            int o = tid >> 5, c = tid & 31;
            wsm[tid] = W1[((o0 + o) * NC + c) * TAPS + 40];
        }
        __syncthreads();
        const int pix = blockIdx.x * 256 + tid;
        float x0[NC];
#pragma unroll
        for (int c = 0; c < NC; ++c) x0[c] = x[c * NPIX + pix];
        float a0 = 0.f, a1 = 0.f, a2 = 0.f, a3 = 0.f;
#pragma unroll
        for (int c = 0; c < NC; ++c) {
            float xv = x0[c];
            a0 = fmaf(xv, wsm[0 * NC + c], a0);
            a1 = fmaf(xv, wsm[1 * NC + c], a1);
            a2 = fmaf(xv, wsm[2 * NC + c], a2);
            a3 = fmaf(xv, wsm[3 * NC + c], a3);
        }
        h[(o0 + 0) * NPIX + pix] = a0 + b1[o0 + 0];
        h[(o0 + 1) * NPIX + pix] = a1 + b1[o0 + 1];
        h[(o0 + 2) * NPIX + pix] = a2 + b1[o0 + 2];
        h[(o0 + 3) * NPIX + pix] = a3 + b1[o0 + 3];
        return;
    }

    if (y == 49) {
        float4 z = make_float4(0.f, 0.f, 0.f, 0.f);
        for (int t = blockIdx.x * 256 + tid; t < (NO * NPIX) / 4; t += 64 * 256)
            ((float4*)outz)[t] = z;
        return;
    }

    for (int t = blockIdx.x * 256 + tid; t < NW; t += 64 * 256) {
        int o = t / (NC * TAPS);
        int r = t - o * (NC * TAPS);
        int c = r / TAPS;
        int tap = r - c * TAPS;
        int d = (tap * NO + o) * NC + c;
        W1t[d] = W1[t];
        W2t[d] = W2[t];
    }
}

__global__ __launch_bounds__(256) void sparse1_kernel(
    const float* __restrict__ x, const float* __restrict__ W1t,
    const unsigned* __restrict__ cnt, const uint2* __restrict__ list,
    float* __restrict__ h)
{
    sparse_body(x, W1t, cnt, list, h,
                blockIdx.x * 256 + threadIdx.x, gridDim.x * 256);
}

__global__ __launch_bounds__(256) void back_kernel(
    const float* __restrict__ h, const float* __restrict__ W2,
    const float* __restrict__ W2t, const float* __restrict__ b2,
    const unsigned* __restrict__ cnt, const uint2* __restrict__ list,
    float* __restrict__ out)
{
    const int y = blockIdx.y;
    const int tid = threadIdx.x;
    if (y < 8) {
        const int o0 = y * 4;
        __shared__ float wsm[4 * NC];
        if (tid < 128) {
            int o = tid >> 5, c = tid & 31;
            wsm[tid] = W2[((o0 + o) * NC + c) * TAPS + 40];
        }
        __syncthreads();
        const int pix = blockIdx.x * 256 + tid;
        float h0[NC];
#pragma unroll
        for (int c = 0; c < NC; ++c) h0[c] = h[c * NPIX + pix];
        float a0 = 0.f, a1 = 0.f, a2 = 0.f, a3 = 0.f;
#pragma unroll
        for (int c = 0; c < NC; ++c) {
            float hv = h0[c];
            a0 = fmaf(hv, wsm[0 * NC + c], a0);
            a1 = fmaf(hv, wsm[1 * NC + c], a1);
            a2 = fmaf(hv, wsm[2 * NC + c], a2);
            a3 = fmaf(hv, wsm[3 * NC + c], a3);
        }
        atomicAdd(&out[(o0 + 0) * NPIX + pix], a0 + b2[o0 + 0]);
        atomicAdd(&out[(o0 + 1) * NPIX + pix], a1 + b2[o0 + 1]);
        atomicAdd(&out[(o0 + 2) * NPIX + pix], a2 + b2[o0 + 2]);
        atomicAdd(&out[(o0 + 3) * NPIX + pix], a3 + b2[o0 + 3]);
        return;
    }
    sparse_body(h, W2t, cnt, list, out,
                blockIdx.x * 256 + tid, 64 * 256);
}

// ===========================================================================
// Fallback path B (tiny ws): fused per-layer, original W layout.
// ===========================================================================
#define CHUNK 27
#define NCHUNK 3
#define KMIN 1e-6f
__global__ __launch_bounds__(256) void pac_layer_fuse(
    const float* __restrict__ in, const float* __restrict__ f,
    const float* __restrict__ Wt, const float* __restrict__ bias,
    float* __restrict__ out)
{
    __shared__ float wl[NC * CHUNK * 8];
    const int og = blockIdx.y;
    const int pix = blockIdx.x * 256 + threadIdx.x;
    const int h = pix >> 7, w = pix & (WW - 1);
    float acc[8];
#pragma unroll
    for (int i = 0; i < 8; ++i) acc[i] = 0.f;
    float fc[NC];
#pragma unroll
    for (int c = 0; c < NC; ++c) fc[c] = f[c * NPIX + pix];
    for (int ch = 0; ch < NCHUNK; ++ch) {
        __syncthreads();
        for (int idx = threadIdx.x; idx < NC * CHUNK * 8; idx += 256) {
            int t = idx % CHUNK;
            int c = (idx / CHUNK) % NC;
            int o = idx / (CHUNK * NC);
            wl[(c * CHUNK + t) * 8 + o] =
                Wt[(og * 8 + o) * (NC * TAPS) + c * TAPS + ch * CHUNK + t];
        }
        __syncthreads();
        for (int t = 0; t < CHUNK; ++t) {
            int tap = ch * CHUNK + t;
            int qh = h + (tap / KS) * DIL - PAD;
            int qw = w + (tap % KS) * DIL - PAD;
            bool valid = ((unsigned)qh < HH) & ((unsigned)qw < WW);
            int q = qh * WW + qw;
            float s = 0.f;
#pragma unroll
            for (int c = 0; c < NC; ++c) {
                float fn = valid ? f[c * NPIX + q] : 0.f;
                float d = fn - fc[c];
                s = fmaf(d, d, s);
            }
            float kv = __expf(-0.5f * s);
            if (__all((kv < KMIN) | (!valid))) continue;
            const float* wpp = &wl[t * 8];
#pragma unroll 8
            for (int c = 0; c < NC; ++c) {
                float v = valid ? in[c * NPIX + q] : 0.f;
                v *= kv;
#pragma unroll
                for (int o = 0; o < 8; ++o)
                    acc[o] = fmaf(v, wpp[c * CHUNK * 8 + o], acc[o]);
            }
        }
    }
#pragma unroll
    for (int o = 0; o < 8; ++o)
        out[(og * 8 + o) * NPIX + pix] = acc[o] + bias[og * 8 + o];
}

// ---------------------------------------------------------------------------
extern "C" void kernel_launch(void* const* d_in, const int* in_sizes, int n_in,
                              void* d_out, int out_size, void* d_ws, size_t ws_size,
                              hipStream_t stream)
{
    (void)in_sizes; (void)n_in; (void)out_size;
    const float* x  = (const float*)d_in[0];
    const float* f  = (const float*)d_in[1];
    const float* W1 = (const float*)d_in[2];
    const float* b1 = (const float*)d_in[3];
    const float* W2 = (const float*)d_in[4];
    const float* b2 = (const float*)d_in[5];
    float* out = (float*)d_out;

    float* ws = (float*)d_ws;
    // main (2-dispatch) layout
    float* xT   = ws;                                   // NPIX*NC
    float* kbuf = xT + NPIX * NC;                       // TAPS*NPIX
    float* W1t  = kbuf + TAPS * NPIX;                   // NW
    float* W2t  = W1t + NW;                             // NW
    unsigned char* mask32 = (unsigned char*)(W2t + NW); // NPIX*32 B
    const size_t need_main =
        (size_t)(NPIX * NC + TAPS * NPIX + 2 * NW) * 4
        + (size_t)NPIX * 32;
    // fallback-A layout
    float* hA   = ws;
    float* W1tA = ws + NO * NPIX;
    float* W2tA = W1tA + NW;
    unsigned* cnt = (unsigned*)(W2tA + NW);
    uint2* list = (uint2*)(cnt + 16);
    const size_t need_fb =
        (size_t)(NO * NPIX + 2 * NW + 16) * 4 + (size_t)CAP * 8;

    if (ws_size >= need_main) {
        prep5_kernel<<<dim3(1856), 256, 0, stream>>>(
            x, f, W1, W2, xT, kbuf, mask32, W1t, W2t);
        fused2_kernel<<<dim3(NPIX / 4), 256, 0, stream>>>(
            xT, kbuf, mask32, W1t, W2t, b1, b2, out);
    } else if (ws_size >= need_fb) {
        zero_cnt_kernel<<<dim3(1), 64, 0, stream>>>(cnt);
        front_kernel<<<dim3(64, 51), 256, 0, stream>>>(
            x, f, W1, W2, b1, hA, cnt, list, W1tA, W2tA, out);
        sparse1_kernel<<<dim3(128), 256, 0, stream>>>(x, W1tA, cnt, list, hA);
        back_kernel<<<dim3(64, 9), 256, 0, stream>>>(
            hA, W2, W2tA, b2, cnt, list, out);
    } else {
        float* hbuf = ws;
        pac_layer_fuse<<<dim3(64, 4), 256, 0, stream>>>(x, f, W1, b1, hbuf);
        pac_layer_fuse<<<dim3(64, 4), 256, 0, stream>>>(hbuf, f, W2, b2, out);
    }
}

// Round 15
// 112.079 us; speedup vs baseline: 1.3797x; 1.2294x over previous
//
#include <hip/hip_runtime.h>

#define HH 128
#define WW 128
#define NPIX 16384
#define NC 32
#define NO 32
#define KS 9
#define TAPS 81
#define DIL 2
#define PAD 8
#define SMAX 27.6310211159f   // s <= SMAX <=> exp(-0.5 s) >= 1e-6; dropped-tap bound ~1.4e-5 << tol
#define NW (NO * NC * TAPS)   // 82944
#define CAP 262144            // fallback-A list capacity

// ---------------------------------------------------------------------------
// Per-pixel mask record: 32 bytes, byte iz = i*3+z holds the 3-bit live mask
// for taps j in {3z,3z+1,3z+2} of row i (bytes 27..31 never read).
// Written byte-owned by prep blocks (no atomics), read as 2x uint4.
// ---------------------------------------------------------------------------
#define BUILD_MASK32(P, M0, M1) do {                                        \
        const uint4* mp_ = (const uint4*)(mask32 + (size_t)(P) * 32);       \
        uint4 ma_ = mp_[0], mb_ = mp_[1];                                   \
        unsigned w_[8] = { ma_.x, ma_.y, ma_.z, ma_.w,                      \
                           mb_.x, mb_.y, mb_.z, mb_.w };                    \
        M0 = 0ull; M1 = 0u;                                                 \
        unsigned m9_[9];                                                    \
        _Pragma("unroll")                                                   \
        for (int i_ = 0; i_ < 9; ++i_) {                                    \
            int k0_ = 3 * i_, k1_ = 3 * i_ + 1, k2_ = 3 * i_ + 2;           \
            unsigned b0_ = (w_[k0_ >> 2] >> ((k0_ & 3) * 8)) & 7u;          \
            unsigned b1_ = (w_[k1_ >> 2] >> ((k1_ & 3) * 8)) & 7u;          \
            unsigned b2_ = (w_[k2_ >> 2] >> ((k2_ & 3) * 8)) & 7u;          \
            m9_[i_] = b0_ | (b1_ << 3) | (b2_ << 6);                        \
        }                                                                   \
        _Pragma("unroll")                                                   \
        for (int i_ = 0; i_ < 7; ++i_)                                      \
            M0 |= (unsigned long long)m9_[i_] << (9 * i_);                  \
        M0 |= (unsigned long long)(m9_[7] & 1u) << 63;                      \
        M1 = (m9_[7] >> 1) | (m9_[8] << 8);                                 \
    } while (0)

// ---------------------------------------------------------------------------
// D1 (front2): the r8-proven D1 (114.1 us total) restored verbatim.
// Mutually-independent roles by blockIdx.x:
//   [0,1728)    prep: (i, j-third) per block -> mask32 + kbuf (scalar-gather
//               prep at max TLP: fastest of six prep variants measured,
//               26-54 us band).
//   [1728,2240) dense1: hd = b1 + W1[.,.,center]·x (exact: kv_center = 1).
//   [2240,2368) zero d_out (D2 accumulates with atomics only).
//   [2368,2449) M[T] = W2c @ W1[T] (81 x 32x32 GEMM in LDS).
//   [2449,2513) transpose W1,W2 -> [tap][o][c].
// ---------------------------------------------------------------------------
__global__ __launch_bounds__(256) void front2_kernel(
    const float* __restrict__ x, const float* __restrict__ f,
    const float* __restrict__ W1, const float* __restrict__ W2,
    const float* __restrict__ b1,
    float* __restrict__ hd, float* __restrict__ kbuf,
    unsigned char* __restrict__ mask32, float* __restrict__ Mm,
    float* __restrict__ W1t, float* __restrict__ W2t,
    float* __restrict__ outz)
{
    const int bid = blockIdx.x;
    const int tid = threadIdx.x;
    __shared__ float shbuf[2048];

    if (bid < 1728) {                          // ---- prep
        const int pixblk = bid & 63, iz = bid >> 6;   // iz = i*3+z, 0..26
        const int i = iz / 3, z = iz - 3 * i;
        const int pix = pixblk * 256 + tid;
        const int hh = pix >> 7, ww = pix & (WW - 1);
        float fc[NC];
#pragma unroll
        for (int c = 0; c < NC; ++c) fc[c] = f[c * NPIX + pix];
        const int qh = hh + i * DIL - PAD;
        const bool vh = (unsigned)qh < HH;
        unsigned pmask = 0;
#pragma unroll
        for (int jj = 0; jj < 3; ++jj) {
            int j = 3 * z + jj;
            int qw = ww + j * DIL - PAD;
            bool valid = vh & ((unsigned)qw < WW);
            int q = valid ? (qh * WW + qw) : pix;   // safe masked addr
            float s0 = 0.f, s1 = 0.f, s2 = 0.f, s3 = 0.f;
#pragma unroll
            for (int c4 = 0; c4 < 8; ++c4) {
                float d0 = f[(4 * c4 + 0) * NPIX + q] - fc[4 * c4 + 0];
                float d1 = f[(4 * c4 + 1) * NPIX + q] - fc[4 * c4 + 1];
                float d2 = f[(4 * c4 + 2) * NPIX + q] - fc[4 * c4 + 2];
                float d3 = f[(4 * c4 + 3) * NPIX + q] - fc[4 * c4 + 3];
                s0 = fmaf(d0, d0, s0); s1 = fmaf(d1, d1, s1);
                s2 = fmaf(d2, d2, s2); s3 = fmaf(d3, d3, s3);
            }
            float s = (s0 + s1) + (s2 + s3);
            // OOB taps contribute exactly 0 (x zero-padded) -> drop exactly.
            bool live = valid && (s <= SMAX) && !(i == 4 && j == 4);
            if (live) {
                pmask |= 1u << jj;
                kbuf[(i * KS + j) * NPIX + pix] = __expf(-0.5f * s);
            }
        }
        mask32[(size_t)pix * 32 + iz] = (unsigned char)pmask;  // kills poison
        return;
    }

    if (bid < 2240) {                          // ---- dense1 -> hd
        const int r = bid - 1728;
        const int o0 = (r >> 6) * 4;
        const int pix = (r & 63) * 256 + tid;
        if (tid < 128)
            shbuf[tid] = W1[((o0 + (tid >> 5)) * NC + (tid & 31)) * TAPS + 40];
        __syncthreads();
        float x0[NC];
#pragma unroll
        for (int c = 0; c < NC; ++c) x0[c] = x[c * NPIX + pix];
        float a0 = 0.f, a1 = 0.f, a2 = 0.f, a3 = 0.f;
#pragma unroll
        for (int c = 0; c < NC; ++c) {
            float xv = x0[c];
            a0 = fmaf(xv, shbuf[0 * NC + c], a0);
            a1 = fmaf(xv, shbuf[1 * NC + c], a1);
            a2 = fmaf(xv, shbuf[2 * NC + c], a2);
            a3 = fmaf(xv, shbuf[3 * NC + c], a3);
        }
        hd[(o0 + 0) * NPIX + pix] = a0 + b1[o0 + 0];
        hd[(o0 + 1) * NPIX + pix] = a1 + b1[o0 + 1];
        hd[(o0 + 2) * NPIX + pix] = a2 + b1[o0 + 2];
        hd[(o0 + 3) * NPIX + pix] = a3 + b1[o0 + 3];
        return;
    }

    if (bid < 2368) {                          // ---- zero d_out
        float4 z4 = make_float4(0.f, 0.f, 0.f, 0.f);
        for (int t = (bid - 2240) * 256 + tid; t < (NO * NPIX) / 4;
             t += 128 * 256)
            ((float4*)outz)[t] = z4;
        return;
    }

    if (bid < 2449) {                          // ---- M[T] = W2c @ W1[T]
        const int T = bid - 2368;
        float* w2c_l = shbuf;                  // [o*32+c]
        float* w1t_l = shbuf + 1024;           // [c*32+c']
        for (int t = tid; t < 1024; t += 256) {
            w2c_l[t] = W2[t * TAPS + 40];      // t = o*32+c
            w1t_l[t] = W1[t * TAPS + T];       // t = c*32+c'
        }
        __syncthreads();
        for (int idx = tid; idx < 1024; idx += 256) {
            int o = idx >> 5, cp = idx & 31;
            float acc = 0.f;
#pragma unroll
            for (int c = 0; c < NC; ++c)
                acc = fmaf(w2c_l[o * NC + c], w1t_l[c * NC + cp], acc);
            Mm[(T * NO + o) * NC + cp] = acc;
        }
        return;
    }

    // ---- [2449,2513): transpose W1,W2 -> [tap][o][c]
    for (int t = (bid - 2449) * 256 + tid; t < NW; t += 64 * 256) {
        int o = t / (NC * TAPS);
        int r = t - o * (NC * TAPS);
        int c = r / TAPS;
        int tap = r - c * TAPS;
        int d = (tap * NO + o) * NC + c;
        W1t[d] = W1[t];
        W2t[d] = W2[t];
    }
}

// ---------------------------------------------------------------------------
// D2 (back2): the r8-proven D2 (44.6 us) with ONE tweak: heavy sparse role B
// gets LOW blockIdx (dispatched first) so its long-tail blocks start
// earliest; trivially-parallel dense role A fills in behind. Roles are
// independent and all-atomic into pre-zeroed out -> order-free.
//   role B [0,2048):  one pixel per half-wave. Per live tap T at p
//       (q = p+off(T), kv): (C) kv*W2t[T]·hd(q), (B) kv*M[T]·x(q),
//       (D) kv * sum_{T' live at q} kv' * W2t[T]·(W1t[T']·x(q+off(T'))).
//   role A [2048,2560): out += b2 + W2c·hd(p) (dense, atomic).
// ---------------------------------------------------------------------------
__global__ __launch_bounds__(256) void back2_kernel(
    const float* __restrict__ x, const float* __restrict__ hd,
    const float* __restrict__ kbuf, const unsigned char* __restrict__ mask32,
    const float* __restrict__ Mm, const float* __restrict__ W1t,
    const float* __restrict__ W2t, const float* __restrict__ W2,
    const float* __restrict__ b2, float* __restrict__ out)
{
    const int bid = blockIdx.x;
    const int tid = threadIdx.x;

    if (bid >= 2048) {                         // ---- role A: dense2 (atomic)
        __shared__ float wsm[4 * NC];
        const int r = bid - 2048;
        const int o0 = (r >> 6) * 4;
        const int pix = (r & 63) * 256 + tid;
        if (tid < 128)
            wsm[tid] = W2[((o0 + (tid >> 5)) * NC + (tid & 31)) * TAPS + 40];
        __syncthreads();
        float h0[NC];
#pragma unroll
        for (int c = 0; c < NC; ++c) h0[c] = hd[c * NPIX + pix];
        float a0 = 0.f, a1 = 0.f, a2 = 0.f, a3 = 0.f;
#pragma unroll
        for (int c = 0; c < NC; ++c) {
            float hv = h0[c];
            a0 = fmaf(hv, wsm[0 * NC + c], a0);
            a1 = fmaf(hv, wsm[1 * NC + c], a1);
            a2 = fmaf(hv, wsm[2 * NC + c], a2);
            a3 = fmaf(hv, wsm[3 * NC + c], a3);
        }
        atomicAdd(&out[(o0 + 0) * NPIX + pix], a0 + b2[o0 + 0]);
        atomicAdd(&out[(o0 + 1) * NPIX + pix], a1 + b2[o0 + 1]);
        atomicAdd(&out[(o0 + 2) * NPIX + pix], a2 + b2[o0 + 2]);
        atomicAdd(&out[(o0 + 3) * NPIX + pix], a3 + b2[o0 + 3]);
        return;
    }

    // ---- role B: one pixel per half-wave; empty masks fall through fast.
    __shared__ float u_lds[8][NC];
    const int hw = tid >> 5;                   // 0..7
    const int lane = tid & 31;                 // output o / channel c
    const int p = bid * 8 + hw;

    unsigned long long A0; unsigned A1;
    BUILD_MASK32(p, A0, A1);
    while (A0 || A1) {
        int T;
        if (A0) { T = __builtin_ctzll(A0); A0 &= A0 - 1; }
        else    { T = 64 + __builtin_ctz(A1); A1 &= A1 - 1; }
        const int ii = T / KS, jj = T - KS * ii;
        const int q = p + (ii * DIL - PAD) * WW + (jj * DIL - PAD);
        const float kv = kbuf[T * NPIX + p];

        // per-lane rows of W2t[T] and M[T] into registers (reused by (D))
        float w2r[NC], mr[NC];
        {
            const float4* w2p = (const float4*)(W2t + (T * NO + lane) * NC);
            const float4* mp  = (const float4*)(Mm  + (T * NO + lane) * NC);
#pragma unroll
            for (int c4 = 0; c4 < 8; ++c4) {
                float4 w4 = w2p[c4], m4 = mp[c4];
                w2r[4 * c4 + 0] = w4.x; w2r[4 * c4 + 1] = w4.y;
                w2r[4 * c4 + 2] = w4.z; w2r[4 * c4 + 3] = w4.w;
                mr[4 * c4 + 0] = m4.x; mr[4 * c4 + 1] = m4.y;
                mr[4 * c4 + 2] = m4.z; mr[4 * c4 + 3] = m4.w;
            }
        }

        // (C) + (B): kv * ( W2t[T]·hd(q) + M[T]·x(q) )
        float dot = 0.f;
#pragma unroll
        for (int c = 0; c < NC; ++c) {
            dot = fmaf(w2r[c], hd[c * NPIX + q], dot);
            dot = fmaf(mr[c],  x[c * NPIX + q],  dot);
        }

        // (D): kv * sum_{T' live at q} kv' * W2t[T]·(W1t[T']·x(q'))
        float dsum = 0.f;
        unsigned long long B0; unsigned B1;
        BUILD_MASK32(q, B0, B1);
        while (B0 || B1) {
            int T2;
            if (B0) { T2 = __builtin_ctzll(B0); B0 &= B0 - 1; }
            else    { T2 = 64 + __builtin_ctz(B1); B1 &= B1 - 1; }
            const int i2 = T2 / KS, j2 = T2 - KS * i2;
            const int q2 = q + (i2 * DIL - PAD) * WW + (j2 * DIL - PAD);
            const float kv2 = kbuf[T2 * NPIX + q];
            // u[lane] = sum_c' W1t[T'][lane][c'] * x[c'][q2]
            const float4* w1p = (const float4*)(W1t + (T2 * NO + lane) * NC);
            float u = 0.f;
#pragma unroll
            for (int c4 = 0; c4 < 8; ++c4) {
                float4 w4 = w1p[c4];
                u = fmaf(w4.x, x[(4 * c4 + 0) * NPIX + q2], u);
                u = fmaf(w4.y, x[(4 * c4 + 1) * NPIX + q2], u);
                u = fmaf(w4.z, x[(4 * c4 + 2) * NPIX + q2], u);
                u = fmaf(w4.w, x[(4 * c4 + 3) * NPIX + q2], u);
            }
            u_lds[hw][lane] = u;               // intra-wave DS order
            float dd = 0.f;
#pragma unroll
            for (int c = 0; c < NC; ++c)
                dd = fmaf(w2r[c], u_lds[hw][c], dd);
            dsum = fmaf(kv2, dd, dsum);
        }
        atomicAdd(&out[lane * NPIX + p], kv * (dot + dsum));
    }
}

// ===========================================================================
// Fallback path A (round-5 proven, 126.9 us): 4 classic dispatches.
// ===========================================================================
__global__ __launch_bounds__(64) void zero_cnt_kernel(unsigned* __restrict__ cnt)
{
    if (threadIdx.x == 0) *cnt = 0u;
}

__device__ __forceinline__ void sparse_body(
    const float* __restrict__ in, const float* __restrict__ Wt,
    const unsigned* __restrict__ cnt, const uint2* __restrict__ list,
    float* __restrict__ out, unsigned gid, unsigned stride)
{
    unsigned n = *cnt;
    if (n > CAP) n = CAP;
    const unsigned total = n * 32u;
    for (unsigned it = gid; it < total; it += stride) {
        unsigned e = it >> 5;
        int o = (int)(it & 31u);
        uint2 me = list[e];
        int pix = (int)(me.x & 16383u);
        int T = (int)(me.x >> 14);
        float kv = __uint_as_float(me.y);
        int ii = T / KS, jj = T - KS * ii;
        int q = pix + (ii * DIL - PAD) * WW + (jj * DIL - PAD);
        const float4* __restrict__ wp =
            (const float4*)(Wt + (T * NO + o) * NC);
        float t0 = 0.f, t1 = 0.f, t2 = 0.f, t3 = 0.f;
#pragma unroll
        for (int c4 = 0; c4 < 8; ++c4) {
            float4 w4 = wp[c4];
            t0 = fmaf(in[(4 * c4 + 0) * NPIX + q], w4.x, t0);
            t1 = fmaf(in[(4 * c4 + 1) * NPIX + q], w4.y, t1);
            t2 = fmaf(in[(4 * c4 + 2) * NPIX + q], w4.z, t2);
            t3 = fmaf(in[(4 * c4 + 3) * NPIX + q], w4.w, t3);
        }
        atomicAdd(&out[o * NPIX + pix], kv * ((t0 + t1) + (t2 + t3)));
    }
}

__global__ __launch_bounds__(256) void front_kernel(
    const float* __restrict__ x, const float* __restrict__ f,
    const float* __restrict__ W1, const float* __restrict__ W2,
    const float* __restrict__ b1,
    float* __restrict__ h, unsigned* __restrict__ cnt,
    uint2* __restrict__ list, float* __restrict__ W1t,
    float* __restrict__ W2t, float* __restrict__ outz)
{
    const int y = blockIdx.y;
    const int tid = threadIdx.x;

    if (y < 41) {
        const int pix = blockIdx.x * 256 + tid;
        const int hh = pix >> 7, ww = pix & (WW - 1);
        float fc[NC];
#pragma unroll
        for (int c = 0; c < NC; ++c) fc[c] = f[c * NPIX + pix];
#pragma unroll
        for (int u = 0; u < 2; ++u) {
            int T = 2 * y + u;
            if (T >= TAPS || T == 40) continue;
            int ii = T / KS, jj = T - KS * ii;
            int qh = hh + ii * DIL - PAD;
            int qw = ww + jj * DIL - PAD;
            bool valid = ((unsigned)qh < HH) & ((unsigned)qw < WW);
            int q = valid ? (qh * WW + qw) : pix;
            float s0 = 0.f, s1 = 0.f, s2 = 0.f, s3 = 0.f;
#pragma unroll
            for (int c4 = 0; c4 < 8; ++c4) {
                float d0 = f[(4 * c4 + 0) * NPIX + q] - fc[4 * c4 + 0];
                float d1 = f[(4 * c4 + 1) * NPIX + q] - fc[4 * c4 + 1];
                float d2 = f[(4 * c4 + 2) * NPIX + q] - fc[4 * c4 + 2];
                float d3 = f[(4 * c4 + 3) * NPIX + q] - fc[4 * c4 + 3];
                s0 = fmaf(d0, d0, s0); s1 = fmaf(d1, d1, s1);
                s2 = fmaf(d2, d2, s2); s3 = fmaf(d3, d3, s3);
            }
            float s = (s0 + s1) + (s2 + s3);
            if (valid && (s <= SMAX)) {
                unsigned idx = atomicAdd(cnt, 1u);
                if (idx < CAP)
                    list[idx] = make_uint2(
                        (unsigned)pix | ((unsigned)T << 14),
                        __float_as_uint(__expf(-0.5f * s)));
            }
        }
        return;
    }

    if (y < 49) {
        const int o0 = (y - 41) * 4;
        __shared__ float wsm[4 * NC];
        if (tid < 128) {
            int o = tid >> 5, c = tid & 31;
            wsm[tid] = W1[((o0 + o) * NC + c) * TAPS + 40];
        }
        __syncthreads();
        const int pix = blockIdx.x * 256 + tid;
        float x0[NC];
#pragma unroll
        for (int c = 0; c < NC; ++c) x0[c] = x[c * NPIX + pix];
        float a0 = 0.f, a1 = 0.f, a2 = 0.f, a3 = 0.f;
#pragma unroll
        for (int c = 0; c < NC; ++c) {
            float xv = x0[c];
            a0 = fmaf(xv, wsm[0 * NC + c], a0);
            a1 = fmaf(xv, wsm[1 * NC + c], a1);
            a2 = fmaf(xv, wsm[2 * NC + c], a2);
            a3 = fmaf(xv, wsm[3 * NC + c], a3);
        }
        h[(o0 + 0) * NPIX + pix] = a0 + b1[o0 + 0];
        h[(o0 + 1) * NPIX + pix] = a1 + b1[o0 + 1];
        h[(o0 + 2) * NPIX + pix] = a2 + b1[o0 + 2];
        h[(o0 + 3) * NPIX + pix] = a3 + b1[o0 + 3];
        return;
    }

    if (y == 49) {
        float4 z = make_float4(0.f, 0.f, 0.f, 0.f);
        for (int t = blockIdx.x * 256 + tid; t < (NO * NPIX) / 4; t += 64 * 256)
            ((float4*)outz)[t] = z;
        return;
    }

    for (int t = blockIdx.x * 256 + tid; t < NW; t += 64 * 256) {
        int o = t / (NC * TAPS);
        int r = t - o * (NC * TAPS);
        int c = r / TAPS;
        int tap = r - c * TAPS;
        int d = (tap * NO + o) * NC + c;
        W1t[d] = W1[t];
        W2t[d] = W2[t];
    }
}

__global__ __launch_bounds__(256) void sparse1_kernel(
    const float* __restrict__ x, const float* __restrict__ W1t,
    const unsigned* __restrict__ cnt, const uint2* __restrict__ list,
    float* __restrict__ h)
{
    sparse_body(x, W1t, cnt, list, h,
                blockIdx.x * 256 + threadIdx.x, gridDim.x * 256);
}

__global__ __launch_bounds__(256) void back_kernel(
    const float* __restrict__ h, const float* __restrict__ W2,
    const float* __restrict__ W2t, const float* __restrict__ b2,
    const unsigned* __restrict__ cnt, const uint2* __restrict__ list,
    float* __restrict__ out)
{
    const int y = blockIdx.y;
    const int tid = threadIdx.x;
    if (y < 8) {
        const int o0 = y * 4;
        __shared__ float wsm[4 * NC];
        if (tid < 128) {
            int o = tid >> 5, c = tid & 31;
            wsm[tid] = W2[((o0 + o) * NC + c) * TAPS + 40];
        }
        __syncthreads();
        const int pix = blockIdx.x * 256 + tid;
        float h0[NC];
#pragma unroll
        for (int c = 0; c < NC; ++c) h0[c] = h[c * NPIX + pix];
        float a0 = 0.f, a1 = 0.f, a2 = 0.f, a3 = 0.f;
#pragma unroll
        for (int c = 0; c < NC; ++c) {
            float hv = h0[c];
            a0 = fmaf(hv, wsm[0 * NC + c], a0);
            a1 = fmaf(hv, wsm[1 * NC + c], a1);
            a2 = fmaf(hv, wsm[2 * NC + c], a2);
            a3 = fmaf(hv, wsm[3 * NC + c], a3);
        }
        atomicAdd(&out[(o0 + 0) * NPIX + pix], a0 + b2[o0 + 0]);
        atomicAdd(&out[(o0 + 1) * NPIX + pix], a1 + b2[o0 + 1]);
        atomicAdd(&out[(o0 + 2) * NPIX + pix], a2 + b2[o0 + 2]);
        atomicAdd(&out[(o0 + 3) * NPIX + pix], a3 + b2[o0 + 3]);
        return;
    }
    sparse_body(h, W2t, cnt, list, out,
                blockIdx.x * 256 + tid, 64 * 256);
}

// ===========================================================================
// Fallback path B (tiny ws): fused per-layer, original W layout.
// ===========================================================================
#define CHUNK 27
#define NCHUNK 3
#define KMIN 1e-6f
__global__ __launch_bounds__(256) void pac_layer_fuse(
    const float* __restrict__ in, const float* __restrict__ f,
    const float* __restrict__ Wt, const float* __restrict__ bias,
    float* __restrict__ out)
{
    __shared__ float wl[NC * CHUNK * 8];
    const int og = blockIdx.y;
    const int pix = blockIdx.x * 256 + threadIdx.x;
    const int h = pix >> 7, w = pix & (WW - 1);
    float acc[8];
#pragma unroll
    for (int i = 0; i < 8; ++i) acc[i] = 0.f;
    float fc[NC];
#pragma unroll
    for (int c = 0; c < NC; ++c) fc[c] = f[c * NPIX + pix];
    for (int ch = 0; ch < NCHUNK; ++ch) {
        __syncthreads();
        for (int idx = threadIdx.x; idx < NC * CHUNK * 8; idx += 256) {
            int t = idx % CHUNK;
            int c = (idx / CHUNK) % NC;
            int o = idx / (CHUNK * NC);
            wl[(c * CHUNK + t) * 8 + o] =
                Wt[(og * 8 + o) * (NC * TAPS) + c * TAPS + ch * CHUNK + t];
        }
        __syncthreads();
        for (int t = 0; t < CHUNK; ++t) {
            int tap = ch * CHUNK + t;
            int qh = h + (tap / KS) * DIL - PAD;
            int qw = w + (tap % KS) * DIL - PAD;
            bool valid = ((unsigned)qh < HH) & ((unsigned)qw < WW);
            int q = qh * WW + qw;
            float s = 0.f;
#pragma unroll
            for (int c = 0; c < NC; ++c) {
                float fn = valid ? f[c * NPIX + q] : 0.f;
                float d = fn - fc[c];
                s = fmaf(d, d, s);
            }
            float kv = __expf(-0.5f * s);
            if (__all((kv < KMIN) | (!valid))) continue;
            const float* wpp = &wl[t * 8];
#pragma unroll 8
            for (int c = 0; c < NC; ++c) {
                float v = valid ? in[c * NPIX + q] : 0.f;
                v *= kv;
#pragma unroll
                for (int o = 0; o < 8; ++o)
                    acc[o] = fmaf(v, wpp[c * CHUNK * 8 + o], acc[o]);
            }
        }
    }
#pragma unroll
    for (int o = 0; o < 8; ++o)
        out[(og * 8 + o) * NPIX + pix] = acc[o] + bias[og * 8 + o];
}

// ---------------------------------------------------------------------------
extern "C" void kernel_launch(void* const* d_in, const int* in_sizes, int n_in,
                              void* d_out, int out_size, void* d_ws, size_t ws_size,
                              hipStream_t stream)
{
    (void)in_sizes; (void)n_in; (void)out_size;
    const float* x  = (const float*)d_in[0];
    const float* f  = (const float*)d_in[1];
    const float* W1 = (const float*)d_in[2];
    const float* b1 = (const float*)d_in[3];
    const float* W2 = (const float*)d_in[4];
    const float* b2 = (const float*)d_in[5];
    float* out = (float*)d_out;

    float* ws = (float*)d_ws;
    // main (2-dispatch) layout
    float* hd   = ws;                                   // NO*NPIX
    float* kbuf = hd + NO * NPIX;                       // TAPS*NPIX
    float* W1t  = kbuf + TAPS * NPIX;                   // NW
    float* W2t  = W1t + NW;                             // NW
    float* Mm   = W2t + NW;                             // TAPS*NO*NC
    unsigned char* mask32 = (unsigned char*)(Mm + TAPS * NO * NC); // NPIX*32 B
    const size_t need_main =
        (size_t)(NO * NPIX + TAPS * NPIX + 2 * NW + TAPS * NO * NC) * 4
        + (size_t)NPIX * 32;
    // fallback-A layout
    float* hA   = ws;
    float* W1tA = ws + NO * NPIX;
    float* W2tA = W1tA + NW;
    unsigned* cnt = (unsigned*)(W2tA + NW);
    uint2* list = (uint2*)(cnt + 16);
    const size_t need_fb =
        (size_t)(NO * NPIX + 2 * NW + 16) * 4 + (size_t)CAP * 8;

    if (ws_size >= need_main) {
        front2_kernel<<<dim3(2513), 256, 0, stream>>>(
            x, f, W1, W2, b1, hd, kbuf, mask32, Mm, W1t, W2t, out);
        back2_kernel<<<dim3(2560), 256, 0, stream>>>(
            x, hd, kbuf, mask32, Mm, W1t, W2t, W2, b2, out);
    } else if (ws_size >= need_fb) {
        zero_cnt_kernel<<<dim3(1), 64, 0, stream>>>(cnt);
        front_kernel<<<dim3(64, 51), 256, 0, stream>>>(
            x, f, W1, W2, b1, hA, cnt, list, W1tA, W2tA, out);
        sparse1_kernel<<<dim3(128), 256, 0, stream>>>(x, W1tA, cnt, list, hA);
        back_kernel<<<dim3(64, 9), 256, 0, stream>>>(
            hA, W2, W2tA, b2, cnt, list, out);
    } else {
        float* hbuf = ws;
        pac_layer_fuse<<<dim3(64, 4), 256, 0, stream>>>(x, f, W1, b1, hbuf);
        pac_layer_fuse<<<dim3(64, 4), 256, 0, stream>>>(hbuf, f, W2, b2, out);
    }
}